// Round 25
// baseline (31.657 us; speedup 1.0000x reference)
//
#include <hip/hip_runtime.h>
#include <math.h>

#define BD 8
#define SD 1024
#define ID 64
#define OD 128
#define NBD 6
#define TI 4            // i-tile per nk block
#define SCH 32          // s-chunk per block (Chebyshev re-init interval)
#define SS 8            // s per super-step (one MFMA wave each)
#define WPAD 136        // padded LDS row (bf16 elems)
#define NU (SCH / SS)   // supersteps per block

typedef short bf16x8 __attribute__((ext_vector_type(8)));
typedef float f32x4 __attribute__((ext_vector_type(4)));
typedef ushort ushortx8 __attribute__((ext_vector_type(8)));

__device__ __forceinline__ ushort rne_bf16(float f) {
    union { float f; unsigned u; } cv; cv.f = f;
    return (ushort)((cv.u + 0x7FFFu + ((cv.u >> 16) & 1u)) >> 16);
}
__device__ __forceinline__ float bf16_to_f(ushort u) {
    union { unsigned u; float f; } cv; cv.u = ((unsigned)u) << 16;
    return cv.f;
}
__device__ __forceinline__ bf16x8 pack8(float4 a, float4 b) {
    union { ushort u[8]; bf16x8 v; } p;
    p.u[0] = rne_bf16(a.x); p.u[1] = rne_bf16(a.y);
    p.u[2] = rne_bf16(a.z); p.u[3] = rne_bf16(a.w);
    p.u[4] = rne_bf16(b.x); p.u[5] = rne_bf16(b.y);
    p.u[6] = rne_bf16(b.z); p.u[7] = rne_bf16(b.w);
    return p.v;
}
__device__ __forceinline__ void pack8_split(float4 a, float4 b,
                                            bf16x8* hi, bf16x8* lo) {
    union { ushort u[8]; bf16x8 v; } ph, pl;
    const float e[8] = {a.x, a.y, a.z, a.w, b.x, b.y, b.z, b.w};
    #pragma unroll
    for (int k = 0; k < 8; ++k) {
        const ushort h = rne_bf16(e[k]);
        ph.u[k] = h;
        pl.u[k] = rne_bf16(e[k] - bf16_to_f(h));
    }
    *hi = ph.v; *lo = pl.v;
}

// ---- Kernel A: MFMA projections + LN (R24 body + P-warm tail) --------------
__global__ __launch_bounds__(256) void ln_mfma(
    const float* __restrict__ seq,    // (8,1024,64)
    const float* __restrict__ M,      // (128,64) [i][j]
    const float* __restrict__ resW,   // (128,64) [i][j]
    const float* __restrict__ P,      // (128,128,6) — warmed into L2 only
    const float* __restrict__ gamma,
    const float* __restrict__ beta,
    ushort* __restrict__ xnT,         // ws: (1024,8,128) bf16 [s][b][j]
    float* __restrict__ resid)        // ws: (1024,8,128) f32 [s][b][i]
{
    const int t   = threadIdx.x;
    // XCD-local s mapping: r = XCD, 16 blocks per sc, 2 s per block
    const int r   = blockIdx.x & 7;
    const int k   = blockIdx.x >> 3;          // 0..63
    const int scl = r * 4 + (k >> 4);         // 0..31
    const int s0  = scl * SCH + (k & 15) * 2;

    const int w  = t >> 6;            // wave id -> col strip
    const int l  = t & 63;
    const int lr = l & 15;
    const int lk = l >> 4;

    __shared__ float Ct[16][132];

    bf16x8 ahi[2], alo[2];
    {
        const int ba = lr & 7, sa = lr >> 3;
        const float* __restrict__ arow = &seq[(ba * SD + s0 + sa) * ID];
        #pragma unroll
        for (int ka = 0; ka < 2; ++ka) {
            const float4 v0 = *(const float4*)&arow[ka * 32 + lk * 8];
            const float4 v1 = *(const float4*)&arow[ka * 32 + lk * 8 + 4];
            pack8_split(v0, v1, &ahi[ka], &alo[ka]);
        }
    }
    bf16x8 bfr[2][2][2];
    #pragma unroll
    for (int mat = 0; mat < 2; ++mat) {
        const float* __restrict__ Wm = mat ? resW : M;
        #pragma unroll
        for (int ct = 0; ct < 2; ++ct) {
            const float* __restrict__ wrow = &Wm[(w * 32 + ct * 16 + lr) * ID];
            #pragma unroll
            for (int kb = 0; kb < 2; ++kb) {
                const float4 v0 = *(const float4*)&wrow[kb * 32 + lk * 8];
                const float4 v1 = *(const float4*)&wrow[kb * 32 + lk * 8 + 4];
                bfr[mat][ct][kb] = pack8(v0, v1);
            }
        }
    }

    f32x4 accx[2], accr[2];
    #pragma unroll
    for (int ct = 0; ct < 2; ++ct) {
        f32x4 a4 = {0.f, 0.f, 0.f, 0.f};
        a4 = __builtin_amdgcn_mfma_f32_16x16x32_bf16(alo[0], bfr[0][ct][0], a4, 0, 0, 0);
        a4 = __builtin_amdgcn_mfma_f32_16x16x32_bf16(alo[1], bfr[0][ct][1], a4, 0, 0, 0);
        a4 = __builtin_amdgcn_mfma_f32_16x16x32_bf16(ahi[0], bfr[0][ct][0], a4, 0, 0, 0);
        a4 = __builtin_amdgcn_mfma_f32_16x16x32_bf16(ahi[1], bfr[0][ct][1], a4, 0, 0, 0);
        accx[ct] = a4;
        f32x4 r4 = {0.f, 0.f, 0.f, 0.f};
        r4 = __builtin_amdgcn_mfma_f32_16x16x32_bf16(ahi[0], bfr[1][ct][0], r4, 0, 0, 0);
        r4 = __builtin_amdgcn_mfma_f32_16x16x32_bf16(ahi[1], bfr[1][ct][1], r4, 0, 0, 0);
        accr[ct] = r4;
    }

    #pragma unroll
    for (int ct = 0; ct < 2; ++ct)
        #pragma unroll
        for (int q = 0; q < 4; ++q) {
            const int rr = lk * 4 + q;
            const int b = rr & 7, sl = rr >> 3;
            resid[((s0 + sl) * BD + b) * OD + w * 32 + ct * 16 + lr] = accr[ct][q];
        }
    #pragma unroll
    for (int ct = 0; ct < 2; ++ct)
        #pragma unroll
        for (int q = 0; q < 4; ++q)
            Ct[lk * 4 + q][w * 32 + ct * 16 + lr] = accx[ct][q];
    __syncthreads();

    {
        const int row = t >> 4;
        const int c0  = (t & 15) * 8;
        float sum = 0.f, ssq = 0.f;
        #pragma unroll
        for (int e = 0; e < 8; ++e) {
            const float v = Ct[row][c0 + e];
            sum += v; ssq = fmaf(v, v, ssq);
        }
        #pragma unroll
        for (int m = 1; m < 16; m <<= 1) {
            sum += __shfl_xor(sum, m, 64);
            ssq += __shfl_xor(ssq, m, 64);
        }
        const float mu   = sum * (1.0f / OD);
        const float vr   = ssq * (1.0f / OD) - mu * mu;
        const float rstd = rsqrtf(vr + 1e-5f);

        const float4 g0 = *(const float4*)&gamma[c0];
        const float4 g1 = *(const float4*)&gamma[c0 + 4];
        const float4 b0 = *(const float4*)&beta[c0];
        const float4 b1 = *(const float4*)&beta[c0 + 4];
        const float gv[8] = {g0.x,g0.y,g0.z,g0.w,g1.x,g1.y,g1.z,g1.w};
        const float bv[8] = {b0.x,b0.y,b0.z,b0.w,b1.x,b1.y,b1.z,b1.w};

        union { ushort u[8]; ushortx8 v; } xo;
        #pragma unroll
        for (int e = 0; e < 8; ++e) {
            const float xv = (Ct[row][c0 + e] - mu) * rstd * gv[e] + bv[e];
            xo.u[e] = rne_bf16(xv);
        }
        const int b  = row & 7, sl = row >> 3;
        *(ushortx8*)&xnT[((s0 + sl) * BD + b) * OD + c0] = xo.v;
    }

    // ---- P-warm tail: pull full P into THIS XCD's L2 for nk's block init ---
    {
        const int idx = (blockIdx.x >> 3) * 256 + t;   // 0..16383 per XCD group
        #pragma unroll
        for (int m = 0; m < 6; ++m) {
            const float v = P[idx + m * 16384];        // coalesced, full P cover
            asm volatile("" :: "v"(v));                // keep live (no DCE)
        }
    }
}

// ---- Kernel B: Chebyshev W-gen + MFMA; A-frags DIRECT from global ----------
// Xl eliminated: A loads issue before W-gen (latency hides under VALU);
// B1 orders only Wl. XCD swizzle as R24.
__global__ __launch_bounds__(512, 6) void nk_kernel(
    const float* __restrict__ P,      // (128,128,6) raw [i][j][g]
    const ushort* __restrict__ xnT,   // [s][b][j] bf16
    const float* __restrict__ resid,  // [s][b][i] f32
    float* __restrict__ out)          // (8,1024,128)
{
    // XCD-local tile decode
    const int r  = blockIdx.x & 7;
    const int k  = blockIdx.x >> 3;           // 0..127
    const int sc = r * 4 + (k >> 5);          // 0..31 (same-sc blocks: same XCD)
    const int i0 = (k & 31) * TI;

    const int t  = threadIdx.x;
    const int iw = t >> 7;            // 0..3 local i (W-gen role)
    const int jb = t & 127;
    const int wv = t >> 6;            // 0..7 wave id (MFMA role)
    const int l  = t & 63;

    __shared__ ushort Wl[SS][TI][WPAD];    // 8.7 KB
    __shared__ float  Cst[SS][BD][TI];     // 1 KB epilogue stage

    const int st_ii = t & 3;
    const int st_b  = (t >> 2) & 7;
    const int st_sl = t >> 5;

    // ---- init 6 Chebyshev states for (i0+iw, jb) ----
    float Pv[NBD], kk[NBD], c0[NBD], c1[NBD];
    const int ig = i0 + iw;
    const float s0f = (float)(sc * SCH);
    #pragma unroll
    for (int g = 0; g < NBD; ++g) {
        Pv[g] = P[(ig * OD + jb) * NBD + g];               // L2-hot (ln warmed)
        const float per = (float)(ig * (OD * NBD) + jb * NBD + g + 2); // exact int
        const float rp  = __builtin_amdgcn_rcpf(per);      // revolutions per step
        kk[g] = 2.0f * __builtin_amdgcn_cosf(rp);
        c1[g] = __builtin_amdgcn_cosf(__builtin_amdgcn_fractf(s0f * rp));
        c0[g] = __builtin_amdgcn_cosf(__builtin_amdgcn_fractf((s0f - 1.0f) * rp));
    }

    // per-wave A-fragment base: xn[s=sb+wv][b=l&7][j=(l>>4)*8 + m*32]
    const ushort* __restrict__ abase = xnT + (l & 7) * OD + (l >> 4) * 8;

    for (int u = 0; u < NU; ++u) {
        const int sb = sc * SCH + u * SS;

        // ---- A-frags: 4 direct global b128 loads (issued BEFORE W-gen) ----
        const ushort* __restrict__ arow = abase + (sb + wv) * (BD * OD);
        const bf16x8 af0 = *(const bf16x8*)&arow[0];
        const bf16x8 af1 = *(const bf16x8*)&arow[32];
        const bf16x8 af2 = *(const bf16x8*)&arow[64];
        const bf16x8 af3 = *(const bf16x8*)&arow[96];

        // ---- prefetch resid slice (consumed at store; hides under W-gen) ----
        float rv = 0.f;
        if (t < SS * BD * TI)
            rv = resid[((sb + st_sl) * BD + st_b) * OD + i0 + st_ii];

        // ---- W-gen: 8 s x (i0+iw, jb), 2 FMA/element ----
        #pragma unroll
        for (int ssi = 0; ssi < SS; ++ssi) {
            float wvv = 0.f;
            #pragma unroll
            for (int g = 0; g < NBD; ++g) wvv = fmaf(Pv[g], c1[g], wvv);
            #pragma unroll
            for (int g = 0; g < NBD; ++g) {
                const float cn = fmaf(kk[g], c1[g], -c0[g]);   // Chebyshev step
                c0[g] = c1[g]; c1[g] = cn;
            }
            Wl[ssi][iw][jb] = rne_bf16(wvv);
        }
        __syncthreads();   // B1: Wl ready

        // ---- MFMA: wave wv handles s = sb + wv ----
        {
            f32x4 acc4 = {0.f, 0.f, 0.f, 0.f};
            const bf16x8 b0 = *(const bf16x8*)&Wl[wv][l & 3][0  + (l >> 4) * 8];
            const bf16x8 b1 = *(const bf16x8*)&Wl[wv][l & 3][32 + (l >> 4) * 8];
            const bf16x8 b2 = *(const bf16x8*)&Wl[wv][l & 3][64 + (l >> 4) * 8];
            const bf16x8 b3 = *(const bf16x8*)&Wl[wv][l & 3][96 + (l >> 4) * 8];
            acc4 = __builtin_amdgcn_mfma_f32_16x16x32_bf16(af0, b0, acc4, 0, 0, 0);
            acc4 = __builtin_amdgcn_mfma_f32_16x16x32_bf16(af1, b1, acc4, 0, 0, 0);
            acc4 = __builtin_amdgcn_mfma_f32_16x16x32_bf16(af2, b2, acc4, 0, 0, 0);
            acc4 = __builtin_amdgcn_mfma_f32_16x16x32_bf16(af3, b3, acc4, 0, 0, 0);
            const int col  = l & 15;
            const int rowg = l >> 4;
            if (col < TI && rowg < 2) {
                #pragma unroll
                for (int q = 0; q < 4; ++q)
                    Cst[wv][rowg * 4 + q][col] = acc4[q];
            }
        }
        __syncthreads();   // B2: Cst visible

        // ---- pure store: out = Nk + residual (no load of out) ----
        if (t < SS * BD * TI)
            out[(st_b * SD + sb + st_sl) * OD + i0 + st_ii] = Cst[st_sl][st_b][st_ii] + rv;
        // next superstep's B1 protects Cst (write-after-read) and Wl
    }
}

extern "C" void kernel_launch(void* const* d_in, const int* in_sizes, int n_in,
                              void* d_out, int out_size, void* d_ws, size_t ws_size,
                              hipStream_t stream) {
    const float* seq   = (const float*)d_in[0];
    const float* M     = (const float*)d_in[1];
    const float* P     = (const float*)d_in[2];
    const float* resW  = (const float*)d_in[3];
    const float* gamma = (const float*)d_in[4];
    const float* beta  = (const float*)d_in[5];
    float* out = (float*)d_out;

    ushort* xnT   = (ushort*)d_ws;                      // 2 MB  bf16 [s][b][j]
    float*  resid = (float*)(xnT + SD * BD * OD);       // 4 MB  f32  [s][b][i]

    ln_mfma<<<dim3(SD / 2), dim3(256), 0, stream>>>(seq, M, resW, P, gamma, beta,
                                                    xnT, resid);
    nk_kernel<<<dim3((SD / SCH) * (OD / TI)), dim3(512), 0, stream>>>(
        P, xnT, resid, out);
}

// Round 26
// 24.615 us; speedup vs baseline: 1.2861x; 1.2861x over previous
//
#include <hip/hip_runtime.h>
#include <math.h>

#define BD 8
#define SD 1024
#define ID 64
#define OD 128
#define NBD 6
#define TI 4            // i-tile per nk block
#define SCH 32          // s-chunk per block (Chebyshev re-init interval)
#define SS 8            // s per super-step (one MFMA wave each)
#define WPAD 136        // padded LDS row (bf16 elems)
#define NU (SCH / SS)   // supersteps per block

typedef short bf16x8 __attribute__((ext_vector_type(8)));
typedef float f32x4 __attribute__((ext_vector_type(4)));
typedef ushort ushortx8 __attribute__((ext_vector_type(8)));

__device__ __forceinline__ ushort rne_bf16(float f) {
    union { float f; unsigned u; } cv; cv.f = f;
    return (ushort)((cv.u + 0x7FFFu + ((cv.u >> 16) & 1u)) >> 16);
}
__device__ __forceinline__ float bf16_to_f(ushort u) {
    union { unsigned u; float f; } cv; cv.u = ((unsigned)u) << 16;
    return cv.f;
}
__device__ __forceinline__ bf16x8 pack8(float4 a, float4 b) {
    union { ushort u[8]; bf16x8 v; } p;
    p.u[0] = rne_bf16(a.x); p.u[1] = rne_bf16(a.y);
    p.u[2] = rne_bf16(a.z); p.u[3] = rne_bf16(a.w);
    p.u[4] = rne_bf16(b.x); p.u[5] = rne_bf16(b.y);
    p.u[6] = rne_bf16(b.z); p.u[7] = rne_bf16(b.w);
    return p.v;
}
__device__ __forceinline__ void pack8_split(float4 a, float4 b,
                                            bf16x8* hi, bf16x8* lo) {
    union { ushort u[8]; bf16x8 v; } ph, pl;
    const float e[8] = {a.x, a.y, a.z, a.w, b.x, b.y, b.z, b.w};
    #pragma unroll
    for (int k = 0; k < 8; ++k) {
        const ushort h = rne_bf16(e[k]);
        ph.u[k] = h;
        pl.u[k] = rne_bf16(e[k] - bf16_to_f(h));
    }
    *hi = ph.v; *lo = pl.v;
}

// ---- Kernel A: MFMA projections + LN (XCD-swizzled s mapping) --------------
// XCD locality: s-chunk sc is written by blocks with bid%8 == sc>>2, matching
// nk's reader placement (same L2).
__global__ __launch_bounds__(256) void ln_mfma(
    const float* __restrict__ seq,    // (8,1024,64)
    const float* __restrict__ M,      // (128,64) [i][j]
    const float* __restrict__ resW,   // (128,64) [i][j]
    const float* __restrict__ gamma,
    const float* __restrict__ beta,
    ushort* __restrict__ xnT,         // ws: (1024,8,128) bf16 [s][b][j]
    float* __restrict__ resid)        // ws: (1024,8,128) f32 [s][b][i]
{
    const int t   = threadIdx.x;
    // XCD-local s mapping: r = XCD, 16 blocks per sc, 2 s per block
    const int r   = blockIdx.x & 7;
    const int k   = blockIdx.x >> 3;          // 0..63
    const int scl = r * 4 + (k >> 4);         // 0..31
    const int s0  = scl * SCH + (k & 15) * 2;

    const int w  = t >> 6;            // wave id -> col strip
    const int l  = t & 63;
    const int lr = l & 15;
    const int lk = l >> 4;

    __shared__ float Ct[16][132];

    bf16x8 ahi[2], alo[2];
    {
        const int ba = lr & 7, sa = lr >> 3;
        const float* __restrict__ arow = &seq[(ba * SD + s0 + sa) * ID];
        #pragma unroll
        for (int ka = 0; ka < 2; ++ka) {
            const float4 v0 = *(const float4*)&arow[ka * 32 + lk * 8];
            const float4 v1 = *(const float4*)&arow[ka * 32 + lk * 8 + 4];
            pack8_split(v0, v1, &ahi[ka], &alo[ka]);
        }
    }
    bf16x8 bfr[2][2][2];
    #pragma unroll
    for (int mat = 0; mat < 2; ++mat) {
        const float* __restrict__ Wm = mat ? resW : M;
        #pragma unroll
        for (int ct = 0; ct < 2; ++ct) {
            const float* __restrict__ wrow = &Wm[(w * 32 + ct * 16 + lr) * ID];
            #pragma unroll
            for (int kb = 0; kb < 2; ++kb) {
                const float4 v0 = *(const float4*)&wrow[kb * 32 + lk * 8];
                const float4 v1 = *(const float4*)&wrow[kb * 32 + lk * 8 + 4];
                bfr[mat][ct][kb] = pack8(v0, v1);
            }
        }
    }

    f32x4 accx[2], accr[2];
    #pragma unroll
    for (int ct = 0; ct < 2; ++ct) {
        f32x4 a4 = {0.f, 0.f, 0.f, 0.f};
        a4 = __builtin_amdgcn_mfma_f32_16x16x32_bf16(alo[0], bfr[0][ct][0], a4, 0, 0, 0);
        a4 = __builtin_amdgcn_mfma_f32_16x16x32_bf16(alo[1], bfr[0][ct][1], a4, 0, 0, 0);
        a4 = __builtin_amdgcn_mfma_f32_16x16x32_bf16(ahi[0], bfr[0][ct][0], a4, 0, 0, 0);
        a4 = __builtin_amdgcn_mfma_f32_16x16x32_bf16(ahi[1], bfr[0][ct][1], a4, 0, 0, 0);
        accx[ct] = a4;
        f32x4 r4 = {0.f, 0.f, 0.f, 0.f};
        r4 = __builtin_amdgcn_mfma_f32_16x16x32_bf16(ahi[0], bfr[1][ct][0], r4, 0, 0, 0);
        r4 = __builtin_amdgcn_mfma_f32_16x16x32_bf16(ahi[1], bfr[1][ct][1], r4, 0, 0, 0);
        accr[ct] = r4;
    }

    #pragma unroll
    for (int ct = 0; ct < 2; ++ct)
        #pragma unroll
        for (int q = 0; q < 4; ++q) {
            const int rr = lk * 4 + q;
            const int b = rr & 7, sl = rr >> 3;
            resid[((s0 + sl) * BD + b) * OD + w * 32 + ct * 16 + lr] = accr[ct][q];
        }
    #pragma unroll
    for (int ct = 0; ct < 2; ++ct)
        #pragma unroll
        for (int q = 0; q < 4; ++q)
            Ct[lk * 4 + q][w * 32 + ct * 16 + lr] = accx[ct][q];
    __syncthreads();

    {
        const int row = t >> 4;
        const int c0  = (t & 15) * 8;
        float sum = 0.f, ssq = 0.f;
        #pragma unroll
        for (int e = 0; e < 8; ++e) {
            const float v = Ct[row][c0 + e];
            sum += v; ssq = fmaf(v, v, ssq);
        }
        #pragma unroll
        for (int m = 1; m < 16; m <<= 1) {
            sum += __shfl_xor(sum, m, 64);
            ssq += __shfl_xor(ssq, m, 64);
        }
        const float mu   = sum * (1.0f / OD);
        const float vr   = ssq * (1.0f / OD) - mu * mu;
        const float rstd = rsqrtf(vr + 1e-5f);

        const float4 g0 = *(const float4*)&gamma[c0];
        const float4 g1 = *(const float4*)&gamma[c0 + 4];
        const float4 b0 = *(const float4*)&beta[c0];
        const float4 b1 = *(const float4*)&beta[c0 + 4];
        const float gv[8] = {g0.x,g0.y,g0.z,g0.w,g1.x,g1.y,g1.z,g1.w};
        const float bv[8] = {b0.x,b0.y,b0.z,b0.w,b1.x,b1.y,b1.z,b1.w};

        union { ushort u[8]; ushortx8 v; } xo;
        #pragma unroll
        for (int e = 0; e < 8; ++e) {
            const float xv = (Ct[row][c0 + e] - mu) * rstd * gv[e] + bv[e];
            xo.u[e] = rne_bf16(xv);
        }
        const int b  = row & 7, sl = row >> 3;
        *(ushortx8*)&xnT[((s0 + sl) * BD + b) * OD + c0] = xo.v;
    }
}

// ---- Kernel B: Chebyshev W-gen + MFMA, pure stores (validated R21 body) ----
// XCD-swizzled tile mapping: all 32 i-tile blocks of one sc share bid%8
// (same XCD) -> xnT slice pulled into that L2 once; ln wrote it there too.
__global__ __launch_bounds__(512, 6) void nk_kernel(
    const float* __restrict__ P,      // (128,128,6) raw [i][j][g]
    const ushort* __restrict__ xnT,   // [s][b][j] bf16
    const float* __restrict__ resid,  // [s][b][i] f32
    float* __restrict__ out)          // (8,1024,128)
{
    // XCD-local tile decode
    const int r  = blockIdx.x & 7;
    const int k  = blockIdx.x >> 3;           // 0..127
    const int sc = r * 4 + (k >> 5);          // 0..31 (same-sc blocks: same XCD)
    const int i0 = (k & 31) * TI;

    const int t  = threadIdx.x;
    const int iw = t >> 7;            // 0..3 local i (W-gen role)
    const int jb = t & 127;
    const int wv = t >> 6;            // 0..7 wave id (MFMA role)
    const int l  = t & 63;

    __shared__ ushort Wl[SS][TI][WPAD];    // 8.7 KB
    __shared__ ushort Xl[SS][BD][WPAD];    // 17.4 KB
    __shared__ float  Cst[SS][BD][TI];     // 1 KB epilogue stage

    const int st_ii = t & 3;
    const int st_b  = (t >> 2) & 7;
    const int st_sl = t >> 5;

    // ---- init 6 Chebyshev states for (i0+iw, jb) ----
    float Pv[NBD], kk[NBD], c0[NBD], c1[NBD];
    const int ig = i0 + iw;
    const float s0f = (float)(sc * SCH);
    #pragma unroll
    for (int g = 0; g < NBD; ++g) {
        Pv[g] = P[(ig * OD + jb) * NBD + g];               // L2/L3, once/block
        const float per = (float)(ig * (OD * NBD) + jb * NBD + g + 2); // exact int
        const float rp  = __builtin_amdgcn_rcpf(per);      // revolutions per step
        kk[g] = 2.0f * __builtin_amdgcn_cosf(rp);
        c1[g] = __builtin_amdgcn_cosf(__builtin_amdgcn_fractf(s0f * rp));
        c0[g] = __builtin_amdgcn_cosf(__builtin_amdgcn_fractf((s0f - 1.0f) * rp));
    }

    for (int u = 0; u < NU; ++u) {
        const int sb = sc * SCH + u * SS;

        // ---- prefetch resid slice (consumed at store; hides under W-gen) ----
        float rv = 0.f;
        if (t < SS * BD * TI)
            rv = resid[((sb + st_sl) * BD + st_b) * OD + i0 + st_ii];

        // ---- stage xn tile: 8s x 8b x 128j bf16 = 16 KB (coalesced uint4) ----
        {
            const uint4* __restrict__ src = (const uint4*)(xnT + sb * (BD * OD));
            #pragma unroll
            for (int rr = 0; rr < 2; ++rr) {
                const int e  = t + 512 * rr;      // uint4 index (1024 total)
                const uint4 v = src[e];
                const int eo = e << 3;            // bf16 elem offset
                const int si = eo >> 10;
                const int b  = (eo >> 7) & 7;
                const int j0 = eo & 127;
                *(uint4*)&Xl[si][b][j0] = v;
            }
        }
        // ---- W-gen: 8 s x (i0+iw, jb), 2 FMA/element ----
        #pragma unroll
        for (int ssi = 0; ssi < SS; ++ssi) {
            float wvv = 0.f;
            #pragma unroll
            for (int g = 0; g < NBD; ++g) wvv = fmaf(Pv[g], c1[g], wvv);
            #pragma unroll
            for (int g = 0; g < NBD; ++g) {
                const float cn = fmaf(kk[g], c1[g], -c0[g]);   // Chebyshev step
                c0[g] = c1[g]; c1[g] = cn;
            }
            Wl[ssi][iw][jb] = rne_bf16(wvv);
        }
        __syncthreads();   // B1: Wl + Xl ready

        // ---- MFMA: wave wv handles s = sb + wv ----
        {
            f32x4 acc4 = {0.f, 0.f, 0.f, 0.f};
            #pragma unroll
            for (int m = 0; m < 4; ++m) {
                const bf16x8 a = *(const bf16x8*)&Xl[wv][l & 7][m * 32 + (l >> 4) * 8];
                const bf16x8 b = *(const bf16x8*)&Wl[wv][l & 3][m * 32 + (l >> 4) * 8];
                acc4 = __builtin_amdgcn_mfma_f32_16x16x32_bf16(a, b, acc4, 0, 0, 0);
            }
            const int col  = l & 15;
            const int rowg = l >> 4;
            if (col < TI && rowg < 2) {
                #pragma unroll
                for (int q = 0; q < 4; ++q)
                    Cst[wv][rowg * 4 + q][col] = acc4[q];
            }
        }
        __syncthreads();   // B2: Cst visible

        // ---- pure store: out = Nk + residual (no load of out) ----
        if (t < SS * BD * TI)
            out[(st_b * SD + sb + st_sl) * OD + i0 + st_ii] = Cst[st_sl][st_b][st_ii] + rv;
        // next superstep's B1 protects Cst (write-after-read) and Wl/Xl
    }
}

extern "C" void kernel_launch(void* const* d_in, const int* in_sizes, int n_in,
                              void* d_out, int out_size, void* d_ws, size_t ws_size,
                              hipStream_t stream) {
    const float* seq   = (const float*)d_in[0];
    const float* M     = (const float*)d_in[1];
    const float* P     = (const float*)d_in[2];
    const float* resW  = (const float*)d_in[3];
    const float* gamma = (const float*)d_in[4];
    const float* beta  = (const float*)d_in[5];
    float* out = (float*)d_out;

    ushort* xnT   = (ushort*)d_ws;                      // 2 MB  bf16 [s][b][j]
    float*  resid = (float*)(xnT + SD * BD * OD);       // 4 MB  f32  [s][b][i]

    ln_mfma<<<dim3(SD / 2), dim3(256), 0, stream>>>(seq, M, resW, gamma, beta,
                                                    xnT, resid);
    nk_kernel<<<dim3((SD / SCH) * (OD / TI)), dim3(512), 0, stream>>>(
        P, xnT, resid, out);
}

// Round 27
// 24.486 us; speedup vs baseline: 1.2929x; 1.0053x over previous
//
#include <hip/hip_runtime.h>
#include <math.h>

#define BD 8
#define SD 1024
#define ID 64
#define OD 128
#define NBD 6
#define TI 4            // i-tile per nk block
#define SCH 32          // s-chunk per block (Chebyshev re-init interval)
#define SS 8            // s per super-step (one MFMA wave each)
#define WPAD 136        // padded LDS row (bf16 elems)
#define NU (SCH / SS)   // supersteps per block

typedef short bf16x8 __attribute__((ext_vector_type(8)));
typedef float f32x4 __attribute__((ext_vector_type(4)));
typedef ushort ushortx8 __attribute__((ext_vector_type(8)));

__device__ __forceinline__ ushort rne_bf16(float f) {
    union { float f; unsigned u; } cv; cv.f = f;
    return (ushort)((cv.u + 0x7FFFu + ((cv.u >> 16) & 1u)) >> 16);
}
__device__ __forceinline__ float bf16_to_f(ushort u) {
    union { unsigned u; float f; } cv; cv.u = ((unsigned)u) << 16;
    return cv.f;
}
__device__ __forceinline__ bf16x8 pack8(float4 a, float4 b) {
    union { ushort u[8]; bf16x8 v; } p;
    p.u[0] = rne_bf16(a.x); p.u[1] = rne_bf16(a.y);
    p.u[2] = rne_bf16(a.z); p.u[3] = rne_bf16(a.w);
    p.u[4] = rne_bf16(b.x); p.u[5] = rne_bf16(b.y);
    p.u[6] = rne_bf16(b.z); p.u[7] = rne_bf16(b.w);
    return p.v;
}
__device__ __forceinline__ void pack8_split(float4 a, float4 b,
                                            bf16x8* hi, bf16x8* lo) {
    union { ushort u[8]; bf16x8 v; } ph, pl;
    const float e[8] = {a.x, a.y, a.z, a.w, b.x, b.y, b.z, b.w};
    #pragma unroll
    for (int k = 0; k < 8; ++k) {
        const ushort h = rne_bf16(e[k]);
        ph.u[k] = h;
        pl.u[k] = rne_bf16(e[k] - bf16_to_f(h));
    }
    *hi = ph.v; *lo = pl.v;
}

// ---- Kernel A: MFMA projections + LN (XCD-swizzled s mapping) --------------
// Residual now stored as bf16 (halves the ws round-trip traffic).
__global__ __launch_bounds__(256) void ln_mfma(
    const float* __restrict__ seq,    // (8,1024,64)
    const float* __restrict__ M,      // (128,64) [i][j]
    const float* __restrict__ resW,   // (128,64) [i][j]
    const float* __restrict__ gamma,
    const float* __restrict__ beta,
    ushort* __restrict__ xnT,         // ws: (1024,8,128) bf16 [s][b][j]
    ushort* __restrict__ residh)      // ws: (1024,8,128) bf16 [s][b][i]
{
    const int t   = threadIdx.x;
    // XCD-local s mapping: r = XCD, 16 blocks per sc, 2 s per block
    const int r   = blockIdx.x & 7;
    const int k   = blockIdx.x >> 3;          // 0..63
    const int scl = r * 4 + (k >> 4);         // 0..31
    const int s0  = scl * SCH + (k & 15) * 2;

    const int w  = t >> 6;            // wave id -> col strip
    const int l  = t & 63;
    const int lr = l & 15;
    const int lk = l >> 4;

    __shared__ float Ct[16][132];

    bf16x8 ahi[2], alo[2];
    {
        const int ba = lr & 7, sa = lr >> 3;
        const float* __restrict__ arow = &seq[(ba * SD + s0 + sa) * ID];
        #pragma unroll
        for (int ka = 0; ka < 2; ++ka) {
            const float4 v0 = *(const float4*)&arow[ka * 32 + lk * 8];
            const float4 v1 = *(const float4*)&arow[ka * 32 + lk * 8 + 4];
            pack8_split(v0, v1, &ahi[ka], &alo[ka]);
        }
    }
    bf16x8 bfr[2][2][2];
    #pragma unroll
    for (int mat = 0; mat < 2; ++mat) {
        const float* __restrict__ Wm = mat ? resW : M;
        #pragma unroll
        for (int ct = 0; ct < 2; ++ct) {
            const float* __restrict__ wrow = &Wm[(w * 32 + ct * 16 + lr) * ID];
            #pragma unroll
            for (int kb = 0; kb < 2; ++kb) {
                const float4 v0 = *(const float4*)&wrow[kb * 32 + lk * 8];
                const float4 v1 = *(const float4*)&wrow[kb * 32 + lk * 8 + 4];
                bfr[mat][ct][kb] = pack8(v0, v1);
            }
        }
    }

    f32x4 accx[2], accr[2];
    #pragma unroll
    for (int ct = 0; ct < 2; ++ct) {
        f32x4 a4 = {0.f, 0.f, 0.f, 0.f};
        a4 = __builtin_amdgcn_mfma_f32_16x16x32_bf16(alo[0], bfr[0][ct][0], a4, 0, 0, 0);
        a4 = __builtin_amdgcn_mfma_f32_16x16x32_bf16(alo[1], bfr[0][ct][1], a4, 0, 0, 0);
        a4 = __builtin_amdgcn_mfma_f32_16x16x32_bf16(ahi[0], bfr[0][ct][0], a4, 0, 0, 0);
        a4 = __builtin_amdgcn_mfma_f32_16x16x32_bf16(ahi[1], bfr[0][ct][1], a4, 0, 0, 0);
        accx[ct] = a4;
        f32x4 r4 = {0.f, 0.f, 0.f, 0.f};
        r4 = __builtin_amdgcn_mfma_f32_16x16x32_bf16(ahi[0], bfr[1][ct][0], r4, 0, 0, 0);
        r4 = __builtin_amdgcn_mfma_f32_16x16x32_bf16(ahi[1], bfr[1][ct][1], r4, 0, 0, 0);
        accr[ct] = r4;
    }

    #pragma unroll
    for (int ct = 0; ct < 2; ++ct)
        #pragma unroll
        for (int q = 0; q < 4; ++q) {
            const int rr = lk * 4 + q;
            const int b = rr & 7, sl = rr >> 3;
            residh[((s0 + sl) * BD + b) * OD + w * 32 + ct * 16 + lr] =
                rne_bf16(accr[ct][q]);
        }
    #pragma unroll
    for (int ct = 0; ct < 2; ++ct)
        #pragma unroll
        for (int q = 0; q < 4; ++q)
            Ct[lk * 4 + q][w * 32 + ct * 16 + lr] = accx[ct][q];
    __syncthreads();

    {
        const int row = t >> 4;
        const int c0  = (t & 15) * 8;
        float sum = 0.f, ssq = 0.f;
        #pragma unroll
        for (int e = 0; e < 8; ++e) {
            const float v = Ct[row][c0 + e];
            sum += v; ssq = fmaf(v, v, ssq);
        }
        #pragma unroll
        for (int m = 1; m < 16; m <<= 1) {
            sum += __shfl_xor(sum, m, 64);
            ssq += __shfl_xor(ssq, m, 64);
        }
        const float mu   = sum * (1.0f / OD);
        const float vr   = ssq * (1.0f / OD) - mu * mu;
        const float rstd = rsqrtf(vr + 1e-5f);

        const float4 g0 = *(const float4*)&gamma[c0];
        const float4 g1 = *(const float4*)&gamma[c0 + 4];
        const float4 b0 = *(const float4*)&beta[c0];
        const float4 b1 = *(const float4*)&beta[c0 + 4];
        const float gv[8] = {g0.x,g0.y,g0.z,g0.w,g1.x,g1.y,g1.z,g1.w};
        const float bv[8] = {b0.x,b0.y,b0.z,b0.w,b1.x,b1.y,b1.z,b1.w};

        union { ushort u[8]; ushortx8 v; } xo;
        #pragma unroll
        for (int e = 0; e < 8; ++e) {
            const float xv = (Ct[row][c0 + e] - mu) * rstd * gv[e] + bv[e];
            xo.u[e] = rne_bf16(xv);
        }
        const int b  = row & 7, sl = row >> 3;
        *(ushortx8*)&xnT[((s0 + sl) * BD + b) * OD + c0] = xo.v;
    }
}

// ---- Kernel B: Chebyshev W-gen + MFMA, pure stores (validated R21 body) ----
// XCD-swizzled tile mapping (R24); resid read as bf16.
__global__ __launch_bounds__(512, 6) void nk_kernel(
    const float* __restrict__ P,      // (128,128,6) raw [i][j][g]
    const ushort* __restrict__ xnT,   // [s][b][j] bf16
    const ushort* __restrict__ residh,// [s][b][i] bf16
    float* __restrict__ out)          // (8,1024,128)
{
    // XCD-local tile decode
    const int r  = blockIdx.x & 7;
    const int k  = blockIdx.x >> 3;           // 0..127
    const int sc = r * 4 + (k >> 5);          // 0..31 (same-sc blocks: same XCD)
    const int i0 = (k & 31) * TI;

    const int t  = threadIdx.x;
    const int iw = t >> 7;            // 0..3 local i (W-gen role)
    const int jb = t & 127;
    const int wv = t >> 6;            // 0..7 wave id (MFMA role)
    const int l  = t & 63;

    __shared__ ushort Wl[SS][TI][WPAD];    // 8.7 KB
    __shared__ ushort Xl[SS][BD][WPAD];    // 17.4 KB
    __shared__ float  Cst[SS][BD][TI];     // 1 KB epilogue stage

    const int st_ii = t & 3;
    const int st_b  = (t >> 2) & 7;
    const int st_sl = t >> 5;

    // ---- init 6 Chebyshev states for (i0+iw, jb) ----
    float Pv[NBD], kk[NBD], c0[NBD], c1[NBD];
    const int ig = i0 + iw;
    const float s0f = (float)(sc * SCH);
    #pragma unroll
    for (int g = 0; g < NBD; ++g) {
        Pv[g] = P[(ig * OD + jb) * NBD + g];               // L2/L3, once/block
        const float per = (float)(ig * (OD * NBD) + jb * NBD + g + 2); // exact int
        const float rp  = __builtin_amdgcn_rcpf(per);      // revolutions per step
        kk[g] = 2.0f * __builtin_amdgcn_cosf(rp);
        c1[g] = __builtin_amdgcn_cosf(__builtin_amdgcn_fractf(s0f * rp));
        c0[g] = __builtin_amdgcn_cosf(__builtin_amdgcn_fractf((s0f - 1.0f) * rp));
    }

    for (int u = 0; u < NU; ++u) {
        const int sb = sc * SCH + u * SS;

        // ---- prefetch resid slice (consumed at store; hides under W-gen) ----
        float rv = 0.f;
        if (t < SS * BD * TI)
            rv = bf16_to_f(residh[((sb + st_sl) * BD + st_b) * OD + i0 + st_ii]);

        // ---- stage xn tile: 8s x 8b x 128j bf16 = 16 KB (coalesced uint4) ----
        {
            const uint4* __restrict__ src = (const uint4*)(xnT + sb * (BD * OD));
            #pragma unroll
            for (int rr = 0; rr < 2; ++rr) {
                const int e  = t + 512 * rr;      // uint4 index (1024 total)
                const uint4 v = src[e];
                const int eo = e << 3;            // bf16 elem offset
                const int si = eo >> 10;
                const int b  = (eo >> 7) & 7;
                const int j0 = eo & 127;
                *(uint4*)&Xl[si][b][j0] = v;
            }
        }
        // ---- W-gen: 8 s x (i0+iw, jb), 2 FMA/element ----
        #pragma unroll
        for (int ssi = 0; ssi < SS; ++ssi) {
            float wvv = 0.f;
            #pragma unroll
            for (int g = 0; g < NBD; ++g) wvv = fmaf(Pv[g], c1[g], wvv);
            #pragma unroll
            for (int g = 0; g < NBD; ++g) {
                const float cn = fmaf(kk[g], c1[g], -c0[g]);   // Chebyshev step
                c0[g] = c1[g]; c1[g] = cn;
            }
            Wl[ssi][iw][jb] = rne_bf16(wvv);
        }
        __syncthreads();   // B1: Wl + Xl ready

        // ---- MFMA: wave wv handles s = sb + wv ----
        {
            f32x4 acc4 = {0.f, 0.f, 0.f, 0.f};
            #pragma unroll
            for (int m = 0; m < 4; ++m) {
                const bf16x8 a = *(const bf16x8*)&Xl[wv][l & 7][m * 32 + (l >> 4) * 8];
                const bf16x8 b = *(const bf16x8*)&Wl[wv][l & 3][m * 32 + (l >> 4) * 8];
                acc4 = __builtin_amdgcn_mfma_f32_16x16x32_bf16(a, b, acc4, 0, 0, 0);
            }
            const int col  = l & 15;
            const int rowg = l >> 4;
            if (col < TI && rowg < 2) {
                #pragma unroll
                for (int q = 0; q < 4; ++q)
                    Cst[wv][rowg * 4 + q][col] = acc4[q];
            }
        }
        __syncthreads();   // B2: Cst visible

        // ---- pure store: out = Nk + residual (no load of out) ----
        if (t < SS * BD * TI)
            out[(st_b * SD + sb + st_sl) * OD + i0 + st_ii] = Cst[st_sl][st_b][st_ii] + rv;
        // next superstep's B1 protects Cst (write-after-read) and Wl/Xl
    }
}

extern "C" void kernel_launch(void* const* d_in, const int* in_sizes, int n_in,
                              void* d_out, int out_size, void* d_ws, size_t ws_size,
                              hipStream_t stream) {
    const float* seq   = (const float*)d_in[0];
    const float* M     = (const float*)d_in[1];
    const float* P     = (const float*)d_in[2];
    const float* resW  = (const float*)d_in[3];
    const float* gamma = (const float*)d_in[4];
    const float* beta  = (const float*)d_in[5];
    float* out = (float*)d_out;

    ushort* xnT    = (ushort*)d_ws;                     // 2 MB bf16 [s][b][j]
    ushort* residh = xnT + SD * BD * OD;                // 2 MB bf16 [s][b][i]

    ln_mfma<<<dim3(SD / 2), dim3(256), 0, stream>>>(seq, M, resW, gamma, beta,
                                                    xnT, residh);
    nk_kernel<<<dim3((SD / SCH) * (OD / TI)), dim3(512), 0, stream>>>(
        P, xnT, residh, out);
}